// Round 8
// baseline (131.545 us; speedup 1.0000x reference)
//
#include <hip/hip_runtime.h>

#define BATCH   8
#define NODES   8192
#define CH      128            // CH_IN == CH_OUT
#define NEXP    64
#define TN      16             // nodes per GEMM tile
#define MAXP    (NODES + NEXP * TN)   // padded sorted-list capacity = 9216
#define NTILES  (MAXP / TN)           // 576 tiles
#define NSORT   64                    // sorter blocks / slices
#define SLICE   (NODES / NSORT)       // 128 sel elems per slice

typedef __attribute__((ext_vector_type(8))) short bf16x8;  // 8 bf16 = 4 VGPRs
typedef __attribute__((ext_vector_type(4))) float f32x4;

typedef const __attribute__((address_space(1))) unsigned int gu32;  // global
typedef __attribute__((address_space(3))) unsigned int lu32;        // LDS

// fp32 -> bf16 RNE via native cast: compiler fuses pairs into
// v_cvt_pk_bf16_f32 (1 instr / 2 elems; m240: scalar cast beats hand-rolled).
__device__ __forceinline__ bf16x8 cvt8(f32x4 lo, f32x4 hi) {
    bf16x8 r;
    #pragma unroll
    for (int i = 0; i < 4; ++i) {
        r[i]     = (short)__builtin_bit_cast(unsigned short, static_cast<__bf16>(lo[i]));
        r[i + 4] = (short)__builtin_bit_cast(unsigned short, static_cast<__bf16>(hi[i]));
    }
    return r;
}

// ---------------------------------------------------------------------------
// SINGLE prep kernel (grid 256 x 256 thr, __launch_bounds__(256,1) -> 1
// block/CU: grid <= CU count, ALL blocks co-resident by capacity, so an
// intra-kernel producer->consumer handoff is deadlock-free).
//  All blocks: W fp32->bf16 convert into SWIZZLED layout (rule #21: 16B chunk
//   (row,chk) stored at (row, chk ^ (row&7)); gemm stages linearly via
//   global_load_lds and applies the same XOR on ds_read -> free 2-way banks).
//  Blocks 0..63 (sorters): slice histogram -> gcnt[blk][e] via device-scope
//   RELEASE stores, then spin with ACQUIRE loads until all 64 partials are
//   >= 0 (workspace poison 0xAA.. is negative; real counts are 0..128).
//   Then padded scan (shfl_up) + cross-block prefix -> scatter slice.
//  Block 63 additionally writes (from the scan, no scatter dependency):
//   pad slots (-1) of each segment tail, texp[tile]=expert for occupied
//   tiles, texp=-1 for global-tail tiles. All these regions are disjoint
//   from every block's scatter targets, so no ordering is required.
// ---------------------------------------------------------------------------
__global__ __launch_bounds__(256, 1)
void prep_kernel(const int* __restrict__ sel, const float* __restrict__ W,
                 short* __restrict__ Wbf, int* __restrict__ sorted,
                 int* __restrict__ texp, int* __restrict__ gcnt)
{
    const int t   = threadIdx.x;
    const int blk = blockIdx.x;
    const bool sorter = (blk < NSORT);

    __shared__ int hist[NEXP];
    __shared__ int part_cnt[4][NEXP];
    __shared__ int part_own[4][NEXP];
    __shared__ int cursor[NEXP];

    // (1) sorters: publish slice histogram ASAP
    if (sorter) {
        if (t < NEXP) hist[t] = 0;
        __syncthreads();
        if (t < SLICE) atomicAdd(&hist[sel[blk * SLICE + t]], 1);
        __syncthreads();
        if (t < NEXP)
            __hip_atomic_store(&gcnt[blk * NEXP + t], hist[t],
                               __ATOMIC_RELEASE, __HIP_MEMORY_SCOPE_AGENT);
    }

    // (2) all blocks: W convert with swizzled chunk placement (2 x 8 floats)
    #pragma unroll
    for (int i = 0; i < 2; ++i) {
        const int g8  = blk * 512 + i * 256 + t;   // global 8-elem group id
        const int e   = g8 >> 11;                  // 2048 groups per expert
        const int row = (g8 & 2047) >> 4;          // 16 chunks per 128-row
        const int chk = g8 & 15;
        const float* ws = W + (size_t)g8 * 8;
        f32x4 lo = *reinterpret_cast<const f32x4*>(ws);
        f32x4 hi = *reinterpret_cast<const f32x4*>(ws + 4);
        short* wd = Wbf + ((size_t)e << 14) + row * CH + ((chk ^ (row & 7)) << 3);
        *reinterpret_cast<bf16x8*>(wd) = cvt8(lo, hi);
    }

    if (!sorter) return;

    // (3) spin-reduce the 64x64 partial-count matrix; wave wv covers 16 slices
    const int wv = t >> 6, l = t & 63;
    {
        int c = 0, o = 0;
        #pragma unroll
        for (int i = 0; i < NSORT / 4; ++i) {
            const int s = wv * (NSORT / 4) + i;
            int g;
            while ((g = __hip_atomic_load(&gcnt[s * NEXP + l],
                        __ATOMIC_ACQUIRE, __HIP_MEMORY_SCOPE_AGENT)) < 0) {}
            c += g;
            o += (s < blk) ? g : 0;
        }
        part_cnt[wv][l] = c;
        part_own[wv][l] = o;
    }
    __syncthreads();

    // (4) wave 0: totals + padded exclusive scan -> segment starts
    if (t < NEXP) {
        const int cnt = part_cnt[0][t] + part_cnt[1][t]
                      + part_cnt[2][t] + part_cnt[3][t];
        const int own = part_own[0][t] + part_own[1][t]
                      + part_own[2][t] + part_own[3][t];
        const int p = (cnt + TN - 1) & ~(TN - 1);
        int scan = p;               // inclusive padded scan over 64 experts
        #pragma unroll
        for (int d = 1; d < NEXP; d <<= 1) {
            int v = __shfl_up(scan, d);
            if (t >= d) scan += v;
        }
        const int start = scan - p;           // 16-aligned by construction
        cursor[t] = start + own;              // this block's scatter cursor

        if (blk == NSORT - 1) {
            // pad slots of expert t's segment tail (disjoint from scatters)
            for (int i = start + cnt; i < start + p; ++i) sorted[i] = -1;
            // tile -> expert for occupied tiles (every such tile has >=1 node)
            for (int tile = start >> 4; tile < (start + p) >> 4; ++tile)
                texp[tile] = t;
            // global-tail tiles get -1
            const int total = __shfl(scan, NEXP - 1);
            for (int tile = (total >> 4) + t; tile < NTILES; tile += NEXP)
                texp[tile] = -1;
        }
    }
    __syncthreads();

    // (5) scatter this block's 128-node slice (positions globally disjoint)
    if (t < SLICE) {
        const int n = blk * SLICE + t;
        const int e = sel[n];
        const int pos = atomicAdd(&cursor[e], 1);
        sorted[pos] = n;
    }
}

// ---------------------------------------------------------------------------
// GEMM, D = W . x^T  (round-5 proven body + texp front-end + XCD remap).
// Block = one tile of 16 nodes, 256 threads = 4 waves; wave w owns output
// rows [w*32, w*32+32) (2 j-tiles) x 128 out-ch (8 ct-tiles).
//  - tile = (bid&7)*72 + bid>>3: consecutive sorted tiles (same expert ->
//    same 32 KB Wbf) land on the same XCD's L2 (bijective, 576 = 8*72).
//  - W tile async-staged via global_load_lds width=16 (linear dest, swizzled
//    source layout); ds_read applies the matching XOR -> free banks.
//  - all x dwordx4 loads issued before the barrier (T14): HBM latency hides
//    under the W DMA + drain.
// ---------------------------------------------------------------------------
__global__ __launch_bounds__(256)
void gemm_kernel(const float* __restrict__ x, const short* __restrict__ Wbf,
                 float* __restrict__ out, const int* __restrict__ sorted,
                 const int* __restrict__ texp)
{
    __shared__ short s_w[CH * CH];           // 32 KB swizzled W tile

    const int tid  = threadIdx.x;
    const int bid  = blockIdx.x;
    const int tile = (bid & 7) * (NTILES / 8) + (bid >> 3);   // XCD-chunked

    int e = texp[tile];                      // block-uniform broadcast load
    if (e < 0) return;                       // pure-pad tile
    e = __builtin_amdgcn_readfirstlane(e);

    const int wave = tid >> 6;               // 0..3
    const int lane = tid & 63;
    const int m16  = lane & 15;              // A row (out-ch) / B col (node-row)
    const int quad = lane >> 4;              // k-subblock / D out-ch group

    // (1) W DMA ASAP — depends only on e. Wave w copies its 8 KB quarter.
    {
        const char* gsrc = (const char*)(Wbf + ((size_t)e << 14))
                         + wave * 8192 + lane * 16;
        char* ldst = (char*)s_w + wave * 8192;
        #pragma unroll
        for (int i = 0; i < 8; ++i) {
            __builtin_amdgcn_global_load_lds(
                (gu32*)(gsrc + i * 1024),
                (lu32*)(ldst + i * 1024),
                16, 0, 0);
        }
    }

    // (2) per-lane node ids for this lane's B-operand rows
    int          nodej[2];
    const float* xrow[2];
    #pragma unroll
    for (int jt = 0; jt < 2; ++jt) {
        int j    = wave * 32 + jt * 16 + m16;       // block-local output row
        int node = sorted[tile * TN + (j >> 3)];
        int b    = j & 7;
        nodej[jt] = node;
        int nd   = (node >= 0) ? node : 0;          // safe address for pads
        xrow[jt] = x + ((size_t)(b * NODES + nd)) * CH;
    }

    // (3) issue ALL x loads — latency hides under W DMA
    f32x4 xl[2][4][2];
    #pragma unroll
    for (int jt = 0; jt < 2; ++jt)
        #pragma unroll
        for (int kk = 0; kk < 4; ++kk) {
            const float* p = xrow[jt] + kk * 32 + quad * 8;
            xl[jt][kk][0] = *reinterpret_cast<const f32x4*>(p);
            xl[jt][kk][1] = *reinterpret_cast<const f32x4*>(p + 4);
        }

    __syncthreads();   // drains vmcnt(0) (x loads + LDS-DMA) + barrier

    // (4) convert x to bf16 fragments (v_cvt_pk)
    bf16x8 xfrag[2][4];
    #pragma unroll
    for (int jt = 0; jt < 2; ++jt)
        #pragma unroll
        for (int kk = 0; kk < 4; ++kk)
            xfrag[jt][kk] = cvt8(xl[jt][kk][0], xl[jt][kk][1]);

    f32x4 acc[2][8];
    #pragma unroll
    for (int jt = 0; jt < 2; ++jt)
        #pragma unroll
        for (int ct = 0; ct < 8; ++ct)
            acc[jt][ct] = (f32x4){0.f, 0.f, 0.f, 0.f};

    // (5) MFMA loop: B-frags from LDS with matching XOR de-swizzle
    #pragma unroll
    for (int kk = 0; kk < 4; ++kk) {
        #pragma unroll
        for (int ct = 0; ct < 8; ++ct) {
            const int row = ct * 16 + m16;
            const bf16x8 wfrag = *reinterpret_cast<const bf16x8*>(
                s_w + row * CH + (((kk * 4 + quad) ^ (row & 7)) << 3));
            acc[0][ct] = __builtin_amdgcn_mfma_f32_16x16x32_bf16(
                             wfrag, xfrag[0][kk], acc[0][ct], 0, 0, 0);
            acc[1][ct] = __builtin_amdgcn_mfma_f32_16x16x32_bf16(
                             wfrag, xfrag[1][kk], acc[1][ct], 0, 0, 0);
        }
    }

    // D layout: col(lane&15) = node-row j, row(quad*4+reg) = out-ch within ct
    // -> lane's f32x4 = out[j][ct*16 + quad*4 .. +3]: one dwordx4 store.
    #pragma unroll
    for (int jt = 0; jt < 2; ++jt) {
        int node = nodej[jt];
        if (node < 0) continue;                     // padded row: drop
        int j = wave * 32 + jt * 16 + m16;
        int b = j & 7;
        float* orow = out + ((size_t)(b * NODES + node)) * CH;
        #pragma unroll
        for (int ct = 0; ct < 8; ++ct)
            *reinterpret_cast<f32x4*>(orow + ct * 16 + quad * 4) = acc[jt][ct];
    }
}

extern "C" void kernel_launch(void* const* d_in, const int* in_sizes, int n_in,
                              void* d_out, int out_size, void* d_ws, size_t ws_size,
                              hipStream_t stream)
{
    const float* x   = (const float*)d_in[0];
    const int*   sel = (const int*)  d_in[1];
    const float* W   = (const float*)d_in[2];
    float*       out = (float*)d_out;

    short* Wbf    = (short*)d_ws;                             // 2 MiB
    int*   sorted = (int*)((char*)d_ws + (size_t)NEXP * CH * CH * sizeof(short));
    int*   gcnt   = sorted + MAXP;                            // 64x64 partials
    int*   texp   = gcnt + NSORT * NEXP;                      // tile -> expert

    prep_kernel<<<256, 256, 0, stream>>>(sel, W, Wbf, sorted, texp, gcnt);
    gemm_kernel<<<NTILES, 256, 0, stream>>>(x, Wbf, out, sorted, texp);
}

// Round 9
// 103.367 us; speedup vs baseline: 1.2726x; 1.2726x over previous
//
#include <hip/hip_runtime.h>

#define BATCH   8
#define NODES   8192
#define CH      128            // CH_IN == CH_OUT
#define NEXP    64
#define TN      16             // nodes per GEMM tile
#define MAXP    (NODES + NEXP * TN)   // padded sorted-list capacity = 9216
#define NTILES  (MAXP / TN)           // 576 tiles
#define NSORT   64                    // sorter blocks / slices
#define SLICE   (NODES / NSORT)       // 128 sel elems per slice

typedef __attribute__((ext_vector_type(8))) short bf16x8;  // 8 bf16 = 4 VGPRs
typedef __attribute__((ext_vector_type(4))) float f32x4;

typedef const __attribute__((address_space(1))) unsigned int gu32;  // global
typedef __attribute__((address_space(3))) unsigned int lu32;        // LDS

// fp32 -> bf16 RNE via native cast: compiler fuses pairs into
// v_cvt_pk_bf16_f32 (1 instr / 2 elems; m240: scalar cast beats hand-rolled).
__device__ __forceinline__ bf16x8 cvt8(f32x4 lo, f32x4 hi) {
    bf16x8 r;
    #pragma unroll
    for (int i = 0; i < 4; ++i) {
        r[i]     = (short)__builtin_bit_cast(unsigned short, static_cast<__bf16>(lo[i]));
        r[i + 4] = (short)__builtin_bit_cast(unsigned short, static_cast<__bf16>(hi[i]));
    }
    return r;
}

// ---------------------------------------------------------------------------
// K1 (grid 256): W convert (SWIZZLED layout) + sorted[]/texp[] -1 fill +
// distributed partial histogram (blocks 0..63, one 128-elem slice of sel).
// Swizzle (rule #21): logical 16B chunk (row, chk) stored at
// (row, chk ^ (row&7)); gemm stages linearly via global_load_lds and applies
// the same XOR on ds_read -> 2-way (free) LDS bank access.
// ---------------------------------------------------------------------------
__global__ __launch_bounds__(256)
void prep1_kernel(const int* __restrict__ sel, const float* __restrict__ W,
                  short* __restrict__ Wbf, int* __restrict__ sorted,
                  int* __restrict__ texp, int* __restrict__ gcnt)
{
    const int t   = threadIdx.x;
    const int blk = blockIdx.x;

    // (a) W convert with swizzled chunk placement: 2 iters x 8 floats
    #pragma unroll
    for (int i = 0; i < 2; ++i) {
        const int g8  = blk * 512 + i * 256 + t;   // global 8-elem group id
        const int e   = g8 >> 11;                  // 2048 groups per expert
        const int row = (g8 & 2047) >> 4;          // 16 chunks per 128-row
        const int chk = g8 & 15;
        const float* ws = W + (size_t)g8 * 8;
        f32x4 lo = *reinterpret_cast<const f32x4*>(ws);
        f32x4 hi = *reinterpret_cast<const f32x4*>(ws + 4);
        short* wd = Wbf + ((size_t)e << 14) + row * CH + ((chk ^ (row & 7)) << 3);
        *reinterpret_cast<bf16x8*>(wd) = cvt8(lo, hi);
    }

    // (b) -1 fill: sorted pads/tail + tile->expert table
    {
        const int si = blk * 256 + t;
        if (si < MAXP)   sorted[si] = -1;
        if (si < NTILES) texp[si]   = -1;
    }

    // (c) partial histogram for slice blk
    if (blk < NSORT) {
        __shared__ int hist[NEXP];
        if (t < NEXP) hist[t] = 0;
        __syncthreads();
        if (t < SLICE) atomicAdd(&hist[sel[blk * SLICE + t]], 1);
        __syncthreads();
        if (t < NEXP) gcnt[blk * NEXP + t] = hist[t];
    }
}

// ---------------------------------------------------------------------------
// K2 (grid 64 x 128 thr): padded segment starts from the 64x64 partial-count
// matrix (unrolled load burst + shfl_up scan) + own cross-block prefix;
// scatter the 128-node slice. Byproduct: texp[tile] = expert for every tile
// that receives at least one node (pure-pad tiles stay -1).
// ---------------------------------------------------------------------------
__global__ __launch_bounds__(128)
void prep2_kernel(const int* __restrict__ sel, const int* __restrict__ gcnt,
                  int* __restrict__ sorted, int* __restrict__ texp)
{
    const int t   = threadIdx.x;
    const int blk = blockIdx.x;

    __shared__ int cursor[NEXP];

    if (t < NEXP) {                 // wave 0: one expert per lane
        int cnt = 0, own = 0;
        #pragma unroll
        for (int s = 0; s < NSORT; ++s) {   // 64 independent loads, one burst
            int g = gcnt[s * NEXP + t];
            own += (s < blk) ? g : 0;
            cnt += g;
        }
        int p = (cnt + TN - 1) & ~(TN - 1);
        int scan = p;               // inclusive padded scan over 64 experts
        #pragma unroll
        for (int d = 1; d < NEXP; d <<= 1) {
            int v = __shfl_up(scan, d);
            if (t >= d) scan += v;
        }
        cursor[t] = (scan - p) + own;   // segment start + cross-block prefix
    }
    __syncthreads();

    if (t < SLICE) {
        int n = blk * SLICE + t;
        int e = sel[n];
        int pos = atomicAdd(&cursor[e], 1);
        sorted[pos] = n;
        // first occupied slot of a 16-aligned tile labels the tile's expert;
        // segment starts are 16-aligned so every non-empty tile gets exactly
        // one writer (all writers of a segment agree on e).
        if ((pos & (TN - 1)) == 0) texp[pos >> 4] = e;
    }
}

// ---------------------------------------------------------------------------
// K3: grouped GEMM, D = W . x^T — round-5 proven body + texp front-end
// (the ONLY delta vs round 5; no nt, no batch-split, no XCD remap).
// Block = one tile of 16 nodes, 256 threads = 4 waves; wave w owns output
// rows [w*32, w*32+32) (2 j-tiles) x 128 out-ch (8 ct-tiles).
//  - e from texp[tile]: one broadcast load, no sel read, no s_nodes LDS,
//    no front __syncthreads -> W DMA issues ~600 cyc earlier.
//  - W tile async-staged via global_load_lds width=16 (linear dest, swizzled
//    source layout); ds_read applies the matching XOR -> free 2-way banks.
//  - all x dwordx4 loads issued before the barrier (T14): HBM latency hides
//    under the W DMA + drain.
// ---------------------------------------------------------------------------
__global__ __launch_bounds__(256)
void gemm_kernel(const float* __restrict__ x, const short* __restrict__ Wbf,
                 float* __restrict__ out, const int* __restrict__ sorted,
                 const int* __restrict__ texp)
{
    __shared__ short s_w[CH * CH];           // 32 KB swizzled W tile

    const int tid  = threadIdx.x;
    const int tile = blockIdx.x;

    int e = texp[tile];                      // block-uniform broadcast load
    if (e < 0) return;                       // pure-pad tile
    e = __builtin_amdgcn_readfirstlane(e);

    const int wave = tid >> 6;               // 0..3
    const int lane = tid & 63;
    const int m16  = lane & 15;              // A row (out-ch) / B col (node-row)
    const int quad = lane >> 4;              // k-subblock / D out-ch group

    // (1) W DMA ASAP — depends only on e. Wave w copies its 8 KB quarter.
    {
        const char* gsrc = (const char*)(Wbf + ((size_t)e << 14))
                         + wave * 8192 + lane * 16;
        char* ldst = (char*)s_w + wave * 8192;
        #pragma unroll
        for (int i = 0; i < 8; ++i) {
            __builtin_amdgcn_global_load_lds(
                (gu32*)(gsrc + i * 1024),
                (lu32*)(ldst + i * 1024),
                16, 0, 0);
        }
    }

    // (2) per-lane node ids for this lane's B-operand rows
    int          nodej[2];
    const float* xrow[2];
    #pragma unroll
    for (int jt = 0; jt < 2; ++jt) {
        int j    = wave * 32 + jt * 16 + m16;       // block-local output row
        int node = sorted[tile * TN + (j >> 3)];
        int b    = j & 7;
        nodej[jt] = node;
        int nd   = (node >= 0) ? node : 0;          // safe address for pads
        xrow[jt] = x + ((size_t)(b * NODES + nd)) * CH;
    }

    // (3) issue ALL x loads — latency hides under W DMA
    f32x4 xl[2][4][2];
    #pragma unroll
    for (int jt = 0; jt < 2; ++jt)
        #pragma unroll
        for (int kk = 0; kk < 4; ++kk) {
            const float* p = xrow[jt] + kk * 32 + quad * 8;
            xl[jt][kk][0] = *reinterpret_cast<const f32x4*>(p);
            xl[jt][kk][1] = *reinterpret_cast<const f32x4*>(p + 4);
        }

    __syncthreads();   // drains vmcnt(0) (x loads + LDS-DMA) + barrier

    // (4) convert x to bf16 fragments (v_cvt_pk)
    bf16x8 xfrag[2][4];
    #pragma unroll
    for (int jt = 0; jt < 2; ++jt)
        #pragma unroll
        for (int kk = 0; kk < 4; ++kk)
            xfrag[jt][kk] = cvt8(xl[jt][kk][0], xl[jt][kk][1]);

    f32x4 acc[2][8];
    #pragma unroll
    for (int jt = 0; jt < 2; ++jt)
        #pragma unroll
        for (int ct = 0; ct < 8; ++ct)
            acc[jt][ct] = (f32x4){0.f, 0.f, 0.f, 0.f};

    // (5) MFMA loop: B-frags from LDS with matching XOR de-swizzle
    #pragma unroll
    for (int kk = 0; kk < 4; ++kk) {
        #pragma unroll
        for (int ct = 0; ct < 8; ++ct) {
            const int row = ct * 16 + m16;
            const bf16x8 wfrag = *reinterpret_cast<const bf16x8*>(
                s_w + row * CH + (((kk * 4 + quad) ^ (row & 7)) << 3));
            acc[0][ct] = __builtin_amdgcn_mfma_f32_16x16x32_bf16(
                             wfrag, xfrag[0][kk], acc[0][ct], 0, 0, 0);
            acc[1][ct] = __builtin_amdgcn_mfma_f32_16x16x32_bf16(
                             wfrag, xfrag[1][kk], acc[1][ct], 0, 0, 0);
        }
    }

    // D layout: col(lane&15) = node-row j, row(quad*4+reg) = out-ch within ct
    // -> lane's f32x4 = out[j][ct*16 + quad*4 .. +3]: one dwordx4 store.
    #pragma unroll
    for (int jt = 0; jt < 2; ++jt) {
        int node = nodej[jt];
        if (node < 0) continue;                     // padded row: drop
        int j = wave * 32 + jt * 16 + m16;
        int b = j & 7;
        float* orow = out + ((size_t)(b * NODES + node)) * CH;
        #pragma unroll
        for (int ct = 0; ct < 8; ++ct)
            *reinterpret_cast<f32x4*>(orow + ct * 16 + quad * 4) = acc[jt][ct];
    }
}

extern "C" void kernel_launch(void* const* d_in, const int* in_sizes, int n_in,
                              void* d_out, int out_size, void* d_ws, size_t ws_size,
                              hipStream_t stream)
{
    const float* x   = (const float*)d_in[0];
    const int*   sel = (const int*)  d_in[1];
    const float* W   = (const float*)d_in[2];
    float*       out = (float*)d_out;

    short* Wbf    = (short*)d_ws;                             // 2 MiB
    int*   sorted = (int*)((char*)d_ws + (size_t)NEXP * CH * CH * sizeof(short));
    int*   gcnt   = sorted + MAXP;                            // 64x64 partials
    int*   texp   = gcnt + NSORT * NEXP;                      // tile -> expert

    prep1_kernel<<<256, 256, 0, stream>>>(sel, W, Wbf, sorted, texp, gcnt);
    prep2_kernel<<<NSORT, 128, 0, stream>>>(sel, gcnt, sorted, texp);
    gemm_kernel<<<NTILES, 256, 0, stream>>>(x, Wbf, out, sorted, texp);
}